// Round 7
// baseline (3066.047 us; speedup 1.0000x reference)
//
#include <hip/hip_runtime.h>
#include <hip/hip_bf16.h>

typedef __attribute__((ext_vector_type(8)))  short          bf16x8;
typedef __attribute__((ext_vector_type(4)))  float          f32x4;
typedef __attribute__((ext_vector_type(8)))  unsigned short us8;

__device__ __forceinline__ unsigned short f2b(float f) {
  union { __hip_bfloat16 h; unsigned short u; } v;
  v.h = __float2bfloat16(f);
  return v.u;
}
__device__ __forceinline__ float b2f(unsigned short u) {
  union { unsigned u; float f; } v; v.u = ((unsigned)u) << 16; return v.f;
}
__device__ __forceinline__ float sigf(float x) {
  return __builtin_amdgcn_rcpf(1.f + __expf(-x));
}
__device__ __forceinline__ float tanhf_(float x) {
  return 2.f * __builtin_amdgcn_rcpf(1.f + __expf(-2.f * x)) - 1.f;
}
__device__ __forceinline__ unsigned cvtpk(float lo, float hi) {
  unsigned d;
  asm("v_cvt_pk_bf16_f32 %0, %1, %2" : "=v"(d) : "v"(lo), "v"(hi));
  return d;
}

// ---------- conversion kernels ----------

__global__ __launch_bounds__(256) void conv_e(const float* __restrict__ in,
                                              unsigned short* __restrict__ out) {
  const size_t i = ((size_t)blockIdx.x * 256 + threadIdx.x) * 8;
  const float4 v0 = *(const float4*)(in + i);
  const float4 v1 = *(const float4*)(in + i + 4);
  us8 o;
  o[0]=f2b(v0.x); o[1]=f2b(v0.y); o[2]=f2b(v0.z); o[3]=f2b(v0.w);
  o[4]=f2b(v1.x); o[5]=f2b(v1.y); o[6]=f2b(v1.z); o[7]=f2b(v1.w);
  *(us8*)(out + i) = o;
}

__global__ __launch_bounds__(256) void conv_wT(const float* __restrict__ W,
                                               unsigned short* __restrict__ WT) {
  __shared__ float tile[64][65];
  const int bx = blockIdx.x & 63;
  const int by = blockIdx.x >> 6;
  const int tc = threadIdx.x & 63, tr = threadIdx.x >> 6;
  #pragma unroll
  for (int i = 0; i < 16; ++i) {
    const int r = i * 4 + tr;
    tile[r][tc] = W[(size_t)(by * 64 + r) * 4096 + bx * 64 + tc];
  }
  __syncthreads();
  #pragma unroll
  for (int i = 0; i < 16; ++i) {
    const int c = i * 4 + tr;
    WT[(size_t)(bx * 64 + c) * 1024 + by * 64 + tc] = f2b(tile[tc][c]);
  }
}

// W_h [1024][4096] f32 -> packed bf16 MFMA-B fragments (unchanged from R6, verified).
__global__ __launch_bounds__(256) void conv_whp(const float* __restrict__ Wh,
                                                unsigned short* __restrict__ Wp) {
  const int id = blockIdx.x * 256 + threadIdx.x;   // 524288 total
  const int l  = id & 63;
  const int kt = (id >> 6) & 7;
  const int nt = (id >> 9) & 7;
  const int kq = (id >> 12) & 3;
  const int n  = id >> 14;
  const int zi = nt * 16 + (l & 15);
  const int col = (zi >> 5) * 1024 + n * 32 + (zi & 31);
  const int k0 = kq * 256 + kt * 32 + (l >> 4) * 8;
  us8 o;
  #pragma unroll
  for (int j = 0; j < 8; ++j) o[j] = f2b(Wh[(size_t)(k0 + j) * 4096 + col]);
  *(us8*)(Wp + (size_t)id * 8) = o;
}

// init out[0] = tagged zeros (f32 0x00000004: denormal ~5.6e-45, tag=4 for t=0).
// sc0 sc1 stores so recur's coherent reads can never see pre-init garbage.
__global__ __launch_bounds__(256) void init_out0(unsigned* __restrict__ out) {
  const unsigned i = (blockIdx.x * 256 + threadIdx.x) * 4;   // 128 blocks
  unsigned* p = out + i;
  const unsigned v = 4u;
  asm volatile("global_store_dword %0, %1, off sc0 sc1" :: "v"(p),     "v"(v) : "memory");
  asm volatile("global_store_dword %0, %1, off sc0 sc1" :: "v"(p + 1), "v"(v) : "memory");
  asm volatile("global_store_dword %0, %1, off sc0 sc1" :: "v"(p + 2), "v"(v) : "memory");
  asm volatile("global_store_dword %0, %1, off sc0 sc1" :: "v"(p + 3), "v"(v) : "memory");
}

// ---------- xproj GEMM (verified structure; bias folded into epilogue) ----------
__global__ __launch_bounds__(256) void gemm_xproj(const unsigned short* __restrict__ A,
                                                  const unsigned short* __restrict__ B,
                                                  const float* __restrict__ bias,
                                                  unsigned short* __restrict__ C) {
  __shared__ unsigned short Alds[128 * 64];
  __shared__ unsigned short Blds[128 * 64];
  const int tid = threadIdx.x, lane = tid & 63, wv = tid >> 6;
  const int wm = wv >> 1, wn = wv & 1;
  const int bn = blockIdx.x & 31, bm = blockIdx.x >> 5;
  f32x4 acc[4][4] = {};
  const int srow = wv * 8 + (lane >> 3);
  const int sinner = (lane & 7) * 8;
  for (int kt = 0; kt < 16; ++kt) {
    #pragma unroll
    for (int rd = 0; rd < 4; ++rd) {
      const int row = rd * 32 + srow;
      const unsigned short* ga = A + (size_t)(bm * 128 + row) * 1024 + kt * 64 + sinner;
      const unsigned short* gb = B + (size_t)(bn * 128 + row) * 1024 + kt * 64 + sinner;
      __builtin_amdgcn_global_load_lds(
          (const __attribute__((address_space(1))) unsigned short*)ga,
          (__attribute__((address_space(3))) unsigned short*)(Alds + rd * 2048 + wv * 512),
          16, 0, 0);
      __builtin_amdgcn_global_load_lds(
          (const __attribute__((address_space(1))) unsigned short*)gb,
          (__attribute__((address_space(3))) unsigned short*)(Blds + rd * 2048 + wv * 512),
          16, 0, 0);
    }
    __syncthreads();
    #pragma unroll
    for (int ks = 0; ks < 2; ++ks) {
      const int kk = ks * 32 + (lane >> 4) * 8;
      bf16x8 af[4], bfr[4];
      #pragma unroll
      for (int mt = 0; mt < 4; ++mt)
        af[mt] = *(const bf16x8*)(Alds + (wm * 64 + mt * 16 + (lane & 15)) * 64 + kk);
      #pragma unroll
      for (int nt = 0; nt < 4; ++nt)
        bfr[nt] = *(const bf16x8*)(Blds + (wn * 64 + nt * 16 + (lane & 15)) * 64 + kk);
      #pragma unroll
      for (int mt = 0; mt < 4; ++mt)
        #pragma unroll
        for (int nt = 0; nt < 4; ++nt)
          acc[mt][nt] = __builtin_amdgcn_mfma_f32_16x16x32_bf16(af[mt], bfr[nt], acc[mt][nt], 0, 0, 0);
    }
    __syncthreads();
  }
  #pragma unroll
  for (int mt = 0; mt < 4; ++mt) {
    const int row0 = bm * 128 + wm * 64 + mt * 16 + (lane >> 4) * 4;
    #pragma unroll
    for (int nt = 0; nt < 4; ++nt) {
      const int col = bn * 128 + wn * 64 + nt * 16 + (lane & 15);
      const float bv = bias[col];
      #pragma unroll
      for (int r = 0; r < 4; ++r)
        C[(size_t)(row0 + r) * 4096 + col] = f2b(acc[mt][nt][r] + bv);
    }
  }
}

// ---------- persistent recurrence kernel (tag-in-mantissa protocol) ----------
// 8 groups x 32 blocks (m=bid>>5 batch stripe of 16 rows, n=bid&31 z-col slot).
// h lives ONLY in out[] as f32 with low-3 mantissa bits = 4|(t&3). Producers
// fire tagged sc0 sc1 stores (no drain, no flag, no barrier). Consumers re-load
// the 16 dwordx4 they need until all 64 embedded tags match, then the data is
// already in registers: cvt_pk -> bf16 frags -> MFMA. One cross-CU round trip
// per step. W_h in 256 VGPRs; zpart LDS reduce (one syncthreads) as in R6.
__global__ __launch_bounds__(256, 1) void lstm_recur(
    const unsigned short* __restrict__ xproj,  // [512*128][4096] bf16 (bias folded)
    const unsigned short* __restrict__ Wp,     // packed fragments
    float* __restrict__ out) {                 // [512][128][1024] f32, tagged
  __shared__ float zpart[10][16][132];         // oversized -> 1 block/CU
  const int tid = threadIdx.x;
  const int lane = tid & 63;
  const int kq = tid >> 6;                     // wave = K-quarter
  const int m = blockIdx.x >> 5;
  const int n = blockIdx.x & 31;

  // W_h fragments -> VGPRs (64 x bf16x8, held whole kernel)
  bf16x8 wf[64];
  {
    const unsigned short* wb = Wp + ((size_t)(n * 4 + kq) * 64) * 512 + lane * 8;
    #pragma unroll
    for (int f = 0; f < 64; ++f) wf[f] = *(const bf16x8*)(wb + f * 512);
  }

  const int r    = tid >> 4;                   // row within stripe (0..15)
  const int hg   = tid & 15;                   // h-col pair group
  const int hc0  = n * 32 + hg * 2;            // h col (0..1023)
  const int grow = m * 16 + r;                 // global batch row

  float cr0 = 0.f, cr1 = 0.f;
  const size_t xbase = (size_t)grow * 4096 + hc0;
  // A-read base (f32): row m*16+(lane&15), col kq*256+(lane>>4)*8; chunk i at +i*32 floats
  const size_t abase = ((size_t)(m * 16 + (lane & 15))) * 1024 + kq * 256 + (lane >> 4) * 8;

  for (int t = 0; t < 511; ++t) {
    // xp loads for THIS step (retired by the poll's vmcnt(0), used at activations)
    unsigned xu0, xu1, xu2, xu3;
    {
      const unsigned short* xpp = xproj + (size_t)t * 524288 + xbase;
      asm volatile("global_load_dword %0, %1, off" : "=v"(xu0) : "v"(xpp));
      asm volatile("global_load_dword %0, %1, off" : "=v"(xu1) : "v"(xpp + 1024));
      asm volatile("global_load_dword %0, %1, off" : "=v"(xu2) : "v"(xpp + 2048));
      asm volatile("global_load_dword %0, %1, off" : "=v"(xu3) : "v"(xpp + 3072));
    }

    const float* ap = out + (size_t)t * 131072 + abase;
    const unsigned tagv = 4u | ((unsigned)t & 3u);
    f32x4 pa0, pa1, pa2, pa3, pa4, pa5, pa6, pa7;
    f32x4 pb0, pb1, pb2, pb3, pb4, pb5, pb6, pb7;

    // ---- poll: re-load h slab until every embedded tag matches ----
    while (true) {
      __builtin_amdgcn_sched_barrier(0);
#define PLD(PA, PB, OFF) \
      asm volatile("global_load_dwordx4 %0, %1, off offset:" #OFF " sc0 sc1"      : "=v"(PA) : "v"(ap)); \
      asm volatile("global_load_dwordx4 %0, %1, off offset:" #OFF "+16 sc0 sc1"   : "=v"(PB) : "v"(ap));
      PLD(pa0, pb0, 0)   PLD(pa1, pb1, 128) PLD(pa2, pb2, 256) PLD(pa3, pb3, 384)
      PLD(pa4, pb4, 512) PLD(pa5, pb5, 640) PLD(pa6, pb6, 768) PLD(pa7, pb7, 896)
#undef PLD
      asm volatile("s_waitcnt vmcnt(0)" ::: "memory");
      __builtin_amdgcn_sched_barrier(0);
      unsigned a0 = 0, a1 = 0, a2 = 0, a3 = 0;
#define TCHK(PA, PB) \
      a0 |= __float_as_uint(PA[0]) ^ tagv; a1 |= __float_as_uint(PA[1]) ^ tagv; \
      a2 |= __float_as_uint(PA[2]) ^ tagv; a3 |= __float_as_uint(PA[3]) ^ tagv; \
      a0 |= __float_as_uint(PB[0]) ^ tagv; a1 |= __float_as_uint(PB[1]) ^ tagv; \
      a2 |= __float_as_uint(PB[2]) ^ tagv; a3 |= __float_as_uint(PB[3]) ^ tagv;
      TCHK(pa0, pb0) TCHK(pa1, pb1) TCHK(pa2, pb2) TCHK(pa3, pb3)
      TCHK(pa4, pb4) TCHK(pa5, pb5) TCHK(pa6, pb6) TCHK(pa7, pb7)
#undef TCHK
      if (__all((int)((((a0 | a1) | (a2 | a3)) & 7u) == 0u))) break;
      __builtin_amdgcn_s_sleep(1);
    }
    __builtin_amdgcn_sched_barrier(0);

    // ---- cvt f32 -> bf16 A-fragments (tags round away) ----
    bf16x8 av0, av1, av2, av3, av4, av5, av6, av7;
#define CVT(AV, PA, PB) { \
      union { unsigned u[4]; bf16x8 v; } c_; \
      c_.u[0] = cvtpk(PA[0], PA[1]); c_.u[1] = cvtpk(PA[2], PA[3]); \
      c_.u[2] = cvtpk(PB[0], PB[1]); c_.u[3] = cvtpk(PB[2], PB[3]); \
      AV = c_.v; }
    CVT(av0, pa0, pb0) CVT(av1, pa1, pb1) CVT(av2, pa2, pb2) CVT(av3, pa3, pb3)
    CVT(av4, pa4, pb4) CVT(av5, pa5, pb5) CVT(av6, pa6, pb6) CVT(av7, pa7, pb7)
#undef CVT

    // ---- MFMA: 8 n-tiles x 8 k-chunks of 16x16x32 ----
    f32x4 ac0 = {0.f,0.f,0.f,0.f}, ac1 = {0.f,0.f,0.f,0.f};
    f32x4 ac2 = {0.f,0.f,0.f,0.f}, ac3 = {0.f,0.f,0.f,0.f};
    f32x4 ac4 = {0.f,0.f,0.f,0.f}, ac5 = {0.f,0.f,0.f,0.f};
    f32x4 ac6 = {0.f,0.f,0.f,0.f}, ac7 = {0.f,0.f,0.f,0.f};
#define MF_STEP(AV, KT) \
    ac0 = __builtin_amdgcn_mfma_f32_16x16x32_bf16(AV, wf[ 0 + KT], ac0, 0, 0, 0); \
    ac1 = __builtin_amdgcn_mfma_f32_16x16x32_bf16(AV, wf[ 8 + KT], ac1, 0, 0, 0); \
    ac2 = __builtin_amdgcn_mfma_f32_16x16x32_bf16(AV, wf[16 + KT], ac2, 0, 0, 0); \
    ac3 = __builtin_amdgcn_mfma_f32_16x16x32_bf16(AV, wf[24 + KT], ac3, 0, 0, 0); \
    ac4 = __builtin_amdgcn_mfma_f32_16x16x32_bf16(AV, wf[32 + KT], ac4, 0, 0, 0); \
    ac5 = __builtin_amdgcn_mfma_f32_16x16x32_bf16(AV, wf[40 + KT], ac5, 0, 0, 0); \
    ac6 = __builtin_amdgcn_mfma_f32_16x16x32_bf16(AV, wf[48 + KT], ac6, 0, 0, 0); \
    ac7 = __builtin_amdgcn_mfma_f32_16x16x32_bf16(AV, wf[56 + KT], ac7, 0, 0, 0);
    MF_STEP(av0, 0) MF_STEP(av1, 1) MF_STEP(av2, 2) MF_STEP(av3, 3)
    MF_STEP(av4, 4) MF_STEP(av5, 5) MF_STEP(av6, 6) MF_STEP(av7, 7)
#undef MF_STEP

    // ---- dump partials: 16x16 C/D: col=lane&15, row=(lane>>4)*4+reg ----
    {
      const int crow = (lane >> 4) * 4, ccol = lane & 15;
#define DUMP(NT, AC) \
      zpart[kq][crow + 0][NT * 16 + ccol] = AC[0]; \
      zpart[kq][crow + 1][NT * 16 + ccol] = AC[1]; \
      zpart[kq][crow + 2][NT * 16 + ccol] = AC[2]; \
      zpart[kq][crow + 3][NT * 16 + ccol] = AC[3];
      DUMP(0, ac0) DUMP(1, ac1) DUMP(2, ac2) DUMP(3, ac3)
      DUMP(4, ac4) DUMP(5, ac5) DUMP(6, ac6) DUMP(7, ac7)
#undef DUMP
    }
    __syncthreads();

    // ---- cross-wave K reduction + activations (bias already in xproj) ----
    float zc[4][2];
    #pragma unroll
    for (int g = 0; g < 4; ++g)
      #pragma unroll
      for (int j = 0; j < 2; ++j) {
        const int col = g * 32 + hg * 2 + j;
        zc[g][j] = (zpart[0][r][col] + zpart[1][r][col])
                 + (zpart[2][r][col] + zpart[3][r][col]);
      }
    __syncthreads();   // zpart reused next step; cheap intra-CU barrier

    float hv0, hv1;
    {
      const float zg = zc[0][0] + b2f((unsigned short)(xu0 & 0xffffu));
      const float zi = zc[1][0] + b2f((unsigned short)(xu1 & 0xffffu));
      const float zf = zc[2][0] + b2f((unsigned short)(xu2 & 0xffffu));
      const float zo = zc[3][0] + b2f((unsigned short)(xu3 & 0xffffu));
      cr0 = tanhf_(zg) * sigf(zi) + cr0 * sigf(zf);
      hv0 = tanhf_(cr0) * sigf(zo);
    }
    {
      const float zg = zc[0][1] + b2f((unsigned short)(xu0 >> 16));
      const float zi = zc[1][1] + b2f((unsigned short)(xu1 >> 16));
      const float zf = zc[2][1] + b2f((unsigned short)(xu2 >> 16));
      const float zo = zc[3][1] + b2f((unsigned short)(xu3 >> 16));
      cr1 = tanhf_(zg) * sigf(zi) + cr1 * sigf(zf);
      hv1 = tanhf_(cr1) * sigf(zo);
    }

    // ---- store h(t+1) = out[t+1] with embedded tag 4|((t+1)&3); fire-and-forget ----
    {
      const unsigned ptag = 4u | ((unsigned)(t + 1) & 3u);
      const unsigned u0 = (__float_as_uint(hv0) & ~7u) | ptag;
      const unsigned u1 = (__float_as_uint(hv1) & ~7u) | ptag;
      const unsigned long long pk = (unsigned long long)u0 | ((unsigned long long)u1 << 32);
      float* hd = out + ((size_t)(t + 1) * 131072) + (size_t)grow * 1024 + hc0;
      asm volatile("global_store_dwordx2 %0, %1, off sc0 sc1" :: "v"(hd), "v"(pk) : "memory");
    }
  }
}

extern "C" void kernel_launch(void* const* d_in, const int* in_sizes, int n_in,
                              void* d_out, int out_size, void* d_ws, size_t ws_size,
                              hipStream_t stream) {
  (void)in_sizes; (void)n_in; (void)out_size; (void)ws_size;
  const float* embeds = (const float*)d_in[0];
  const float* Wx     = (const float*)d_in[1];
  const float* Wh     = (const float*)d_in[2];
  const float* bias   = (const float*)d_in[3];
  float* out = (float*)d_out;

  char* w = (char*)d_ws;
  unsigned short* eb  = (unsigned short*)(w);                 // 134,217,728 B
  unsigned short* WxT = (unsigned short*)(w + 134217728);     //   8,388,608 B
  unsigned short* Whp = (unsigned short*)(w + 142606336);     //   8,388,608 B
  unsigned short* xp  = (unsigned short*)(w + 150994944);     // 536,870,912 B

  conv_e    <<<32768, 256, 0, stream>>>(embeds, eb);
  conv_wT   <<<1024,  256, 0, stream>>>(Wx, WxT);
  conv_whp  <<<2048,  256, 0, stream>>>(Wh, Whp);
  init_out0 <<<128,   256, 0, stream>>>((unsigned*)out);
  gemm_xproj<<<16384, 256, 0, stream>>>(eb, WxT, bias, xp);
  lstm_recur<<<256,   256, 0, stream>>>(xp, Whp, out);
}

// Round 10
// 2918.518 us; speedup vs baseline: 1.0505x; 1.0505x over previous
//
#include <hip/hip_runtime.h>
#include <hip/hip_bf16.h>

typedef __attribute__((ext_vector_type(8)))  short          bf16x8;
typedef __attribute__((ext_vector_type(4)))  float          f32x4;
typedef __attribute__((ext_vector_type(8)))  unsigned short us8;

__device__ __forceinline__ unsigned short f2b(float f) {
  union { __hip_bfloat16 h; unsigned short u; } v;
  v.h = __float2bfloat16(f);
  return v.u;
}
__device__ __forceinline__ float b2f(unsigned short u) {
  union { unsigned u; float f; } v; v.u = ((unsigned)u) << 16; return v.f;
}
__device__ __forceinline__ float sigf(float x) {
  return __builtin_amdgcn_rcpf(1.f + __expf(-x));
}
__device__ __forceinline__ float tanhf_(float x) {
  return 2.f * __builtin_amdgcn_rcpf(1.f + __expf(-2.f * x)) - 1.f;
}

// ---------- conversion kernels ----------

__global__ __launch_bounds__(256) void conv_e(const float* __restrict__ in,
                                              unsigned short* __restrict__ out) {
  const size_t i = ((size_t)blockIdx.x * 256 + threadIdx.x) * 8;
  const float4 v0 = *(const float4*)(in + i);
  const float4 v1 = *(const float4*)(in + i + 4);
  us8 o;
  o[0]=f2b(v0.x); o[1]=f2b(v0.y); o[2]=f2b(v0.z); o[3]=f2b(v0.w);
  o[4]=f2b(v1.x); o[5]=f2b(v1.y); o[6]=f2b(v1.z); o[7]=f2b(v1.w);
  *(us8*)(out + i) = o;
}

__global__ __launch_bounds__(256) void conv_wT(const float* __restrict__ W,
                                               unsigned short* __restrict__ WT) {
  __shared__ float tile[64][65];
  const int bx = blockIdx.x & 63;
  const int by = blockIdx.x >> 6;
  const int tc = threadIdx.x & 63, tr = threadIdx.x >> 6;
  #pragma unroll
  for (int i = 0; i < 16; ++i) {
    const int r = i * 4 + tr;
    tile[r][tc] = W[(size_t)(by * 64 + r) * 4096 + bx * 64 + tc];
  }
  __syncthreads();
  #pragma unroll
  for (int i = 0; i < 16; ++i) {
    const int c = i * 4 + tr;
    WT[(size_t)(bx * 64 + c) * 1024 + by * 64 + tc] = f2b(tile[tc][c]);
  }
}

// W_h [1024][4096] f32 -> packed bf16 MFMA-B fragments (verified R6).
// id = n*16384 + kq*4096 + nt*512 + kt*64 + lane. lane l holds B[k][zcol]:
// k = kq*256 + kt*32 + (l>>4)*8 + j; zi = nt*16 + (l&15);
// zcol = (zi>>5)*1024 + n*32 + (zi&31)  (gate-major 4H).
__global__ __launch_bounds__(256) void conv_whp(const float* __restrict__ Wh,
                                                unsigned short* __restrict__ Wp) {
  const int id = blockIdx.x * 256 + threadIdx.x;   // 524288 total
  const int l  = id & 63;
  const int kt = (id >> 6) & 7;
  const int nt = (id >> 9) & 7;
  const int kq = (id >> 12) & 3;
  const int n  = id >> 14;
  const int zi = nt * 16 + (l & 15);
  const int col = (zi >> 5) * 1024 + n * 32 + (zi & 31);
  const int k0 = kq * 256 + kt * 32 + (l >> 4) * 8;
  us8 o;
  #pragma unroll
  for (int j = 0; j < 8; ++j) o[j] = f2b(Wh[(size_t)(k0 + j) * 4096 + col]);
  *(us8*)(Wp + (size_t)id * 8) = o;
}

// ---------- xproj GEMM (verified m97 structure; + bias fold + XCD swizzle) ----------
__global__ __launch_bounds__(256) void gemm_xproj(const unsigned short* __restrict__ A,
                                                  const unsigned short* __restrict__ B,
                                                  const float* __restrict__ bias,
                                                  unsigned short* __restrict__ C) {
  __shared__ unsigned short Alds[128 * 64];
  __shared__ unsigned short Blds[128 * 64];
  const int tid = threadIdx.x, lane = tid & 63, wv = tid >> 6;
  const int wm = wv >> 1, wn = wv & 1;
  // XCD-aware bijective swizzle (16384 blocks, 16384 % 8 == 0): each XCD gets a
  // contiguous sid range -> A-panel L2 reuse.
  const int sid = (blockIdx.x & 7) * 2048 + (blockIdx.x >> 3);
  const int bn = sid & 31, bm = sid >> 5;
  f32x4 acc[4][4] = {};
  const int srow = wv * 8 + (lane >> 3);
  const int sinner = (lane & 7) * 8;
  for (int kt = 0; kt < 16; ++kt) {
    #pragma unroll
    for (int rd = 0; rd < 4; ++rd) {
      const int row = rd * 32 + srow;
      const unsigned short* ga = A + (size_t)(bm * 128 + row) * 1024 + kt * 64 + sinner;
      const unsigned short* gb = B + (size_t)(bn * 128 + row) * 1024 + kt * 64 + sinner;
      __builtin_amdgcn_global_load_lds(
          (const __attribute__((address_space(1))) unsigned short*)ga,
          (__attribute__((address_space(3))) unsigned short*)(Alds + rd * 2048 + wv * 512),
          16, 0, 0);
      __builtin_amdgcn_global_load_lds(
          (const __attribute__((address_space(1))) unsigned short*)gb,
          (__attribute__((address_space(3))) unsigned short*)(Blds + rd * 2048 + wv * 512),
          16, 0, 0);
    }
    __syncthreads();
    #pragma unroll
    for (int ks = 0; ks < 2; ++ks) {
      const int kk = ks * 32 + (lane >> 4) * 8;
      bf16x8 af[4], bfr[4];
      #pragma unroll
      for (int mt = 0; mt < 4; ++mt)
        af[mt] = *(const bf16x8*)(Alds + (wm * 64 + mt * 16 + (lane & 15)) * 64 + kk);
      #pragma unroll
      for (int nt = 0; nt < 4; ++nt)
        bfr[nt] = *(const bf16x8*)(Blds + (wn * 64 + nt * 16 + (lane & 15)) * 64 + kk);
      #pragma unroll
      for (int mt = 0; mt < 4; ++mt)
        #pragma unroll
        for (int nt = 0; nt < 4; ++nt)
          acc[mt][nt] = __builtin_amdgcn_mfma_f32_16x16x32_bf16(af[mt], bfr[nt], acc[mt][nt], 0, 0, 0);
    }
    __syncthreads();
  }
  #pragma unroll
  for (int mt = 0; mt < 4; ++mt) {
    const int row0 = bm * 128 + wm * 64 + mt * 16 + (lane >> 4) * 4;
    #pragma unroll
    for (int nt = 0; nt < 4; ++nt) {
      const int col = bn * 128 + wn * 64 + nt * 16 + (lane & 15);
      const float bv = bias[col];                 // bias folded HERE (only here)
      #pragma unroll
      for (int r = 0; r < 4; ++r)
        C[(size_t)(row0 + r) * 4096 + col] = f2b(acc[mt][nt][r] + bv);
    }
  }
}

// ---------- persistent recurrence kernel (R6 + per-wave dependency polling) ----------
// 8 groups x 32 blocks (m=bid>>5 stripe of 16 batch rows, n=bid&31 z-col slot).
// W_h slice in 256 VGPRs; A-frags straight from row-major h (sc0 sc1).
// Private flag mailboxes flags[consumer 256][producer 32]; producer broadcasts
// after drain+barrier. NEW: wave kq reads only k in [kq*256,kq*256+256) = h-cols
// of producers n in [kq*8,kq*8+8), so it polls ONLY those 8 flags and starts its
// A-loads/MFMA early; barrier #1 (intra-CU) collects all 4 waves, so all 32
// flags are collectively verified before any h-store of the next step (same
// write-after-read guarantee as R6). Bias is in xp now (NOT added here).
__global__ __launch_bounds__(256, 1) void lstm_recur(
    const unsigned short* __restrict__ xproj,  // [512*128][4096] bf16, bias folded
    const unsigned short* __restrict__ Wp,     // packed fragments
    unsigned short* __restrict__ hbuf,         // [2][128][1024] bf16 row-major
    float* __restrict__ out,                   // [512][128][1024]
    unsigned* __restrict__ flags) {            // [256][32] private mailboxes
  __shared__ float zpart[10][16][132];         // [0..3] used; oversized -> 1 block/CU
  const int tid = threadIdx.x;
  const int lane = tid & 63;
  const int kq = tid >> 6;                     // wave = K-quarter
  const int m = blockIdx.x >> 5;               // group / 16-row batch stripe
  const int n = blockIdx.x & 31;               // 128-z-col slot

  // W_h fragments -> VGPRs (64 x bf16x8, held whole kernel)
  bf16x8 wf[64];
  {
    const unsigned short* wb = Wp + ((size_t)(n * 4 + kq) * 64) * 512 + lane * 8;
    #pragma unroll
    for (int f = 0; f < 64; ++f) wf[f] = *(const bf16x8*)(wb + f * 512);
  }

  const int r    = tid >> 4;                   // row within stripe (0..15)
  const int hg   = tid & 15;                   // h-col pair group
  const int hc0  = n * 32 + hg * 2;            // h col (0..1023)
  const int grow = m * 16 + r;                 // global batch row

  float cr0 = 0.f, cr1 = 0.f;
  const size_t xbase = (size_t)grow * 4096 + hc0;
  unsigned* bcast = flags + (m * 32 + (lane & 31)) * 32 + n;  // producer->consumer slots
  // per-wave dependency poll: wave kq watches producers kq*8 .. kq*8+7
  const unsigned* myf = flags + (size_t)(m * 32 + n) * 32 + kq * 8 + (lane & 7);

  // prologue: xproj loads for step 0
  unsigned xu0, xu1, xu2, xu3;
  {
    const unsigned short* xpp = xproj + xbase;
    asm volatile("global_load_dword %0, %1, off" : "=v"(xu0) : "v"(xpp));
    asm volatile("global_load_dword %0, %1, off" : "=v"(xu1) : "v"(xpp + 1024));
    asm volatile("global_load_dword %0, %1, off" : "=v"(xu2) : "v"(xpp + 2048));
    asm volatile("global_load_dword %0, %1, off" : "=v"(xu3) : "v"(xpp + 3072));
  }

  // A-frag addr: row (lane&15) of stripe, k = kq*256 + (lane>>4)*8 (+kt*32 imm)
  const size_t aoff = ((size_t)(m * 16 + (lane & 15))) * 1024 + kq * 256 + (lane >> 4) * 8;

  for (int t = 0; t < 511; ++t) {
    const unsigned short* ab = hbuf + (t & 1) * 131072 + aoff;

    bf16x8 av0, av1, av2, av3, av4, av5, av6, av7;
    __builtin_amdgcn_sched_barrier(0);
    asm volatile("global_load_dwordx4 %0, %1, off sc0 sc1"            : "=v"(av0) : "v"(ab));
    asm volatile("global_load_dwordx4 %0, %1, off offset:64 sc0 sc1"  : "=v"(av1) : "v"(ab));
    asm volatile("global_load_dwordx4 %0, %1, off offset:128 sc0 sc1" : "=v"(av2) : "v"(ab));
    asm volatile("global_load_dwordx4 %0, %1, off offset:192 sc0 sc1" : "=v"(av3) : "v"(ab));
    asm volatile("global_load_dwordx4 %0, %1, off offset:256 sc0 sc1" : "=v"(av4) : "v"(ab));
    asm volatile("global_load_dwordx4 %0, %1, off offset:320 sc0 sc1" : "=v"(av5) : "v"(ab));
    asm volatile("global_load_dwordx4 %0, %1, off offset:384 sc0 sc1" : "=v"(av6) : "v"(ab));
    asm volatile("global_load_dwordx4 %0, %1, off offset:448 sc0 sc1" : "=v"(av7) : "v"(ab));
    asm volatile("s_waitcnt vmcnt(0)" ::: "memory");
    __builtin_amdgcn_sched_barrier(0);

    // MFMA: 8 n-tiles x 8 k-tiles of 16x16x32; acc reuse distance 8
    f32x4 ac0 = {0.f,0.f,0.f,0.f}, ac1 = {0.f,0.f,0.f,0.f};
    f32x4 ac2 = {0.f,0.f,0.f,0.f}, ac3 = {0.f,0.f,0.f,0.f};
    f32x4 ac4 = {0.f,0.f,0.f,0.f}, ac5 = {0.f,0.f,0.f,0.f};
    f32x4 ac6 = {0.f,0.f,0.f,0.f}, ac7 = {0.f,0.f,0.f,0.f};
#define MF_STEP(AV, KT) \
    ac0 = __builtin_amdgcn_mfma_f32_16x16x32_bf16(AV, wf[ 0 + KT], ac0, 0, 0, 0); \
    ac1 = __builtin_amdgcn_mfma_f32_16x16x32_bf16(AV, wf[ 8 + KT], ac1, 0, 0, 0); \
    ac2 = __builtin_amdgcn_mfma_f32_16x16x32_bf16(AV, wf[16 + KT], ac2, 0, 0, 0); \
    ac3 = __builtin_amdgcn_mfma_f32_16x16x32_bf16(AV, wf[24 + KT], ac3, 0, 0, 0); \
    ac4 = __builtin_amdgcn_mfma_f32_16x16x32_bf16(AV, wf[32 + KT], ac4, 0, 0, 0); \
    ac5 = __builtin_amdgcn_mfma_f32_16x16x32_bf16(AV, wf[40 + KT], ac5, 0, 0, 0); \
    ac6 = __builtin_amdgcn_mfma_f32_16x16x32_bf16(AV, wf[48 + KT], ac6, 0, 0, 0); \
    ac7 = __builtin_amdgcn_mfma_f32_16x16x32_bf16(AV, wf[56 + KT], ac7, 0, 0, 0);
    MF_STEP(av0, 0) MF_STEP(av1, 1) MF_STEP(av2, 2) MF_STEP(av3, 3)
    MF_STEP(av4, 4) MF_STEP(av5, 5) MF_STEP(av6, 6) MF_STEP(av7, 7)
#undef MF_STEP

    // dump partials: 16x16 C/D: col=lane&15, row=(lane>>4)*4+reg
    {
      const int crow = (lane >> 4) * 4, ccol = lane & 15;
#define DUMP(NT, AC) \
      zpart[kq][crow + 0][NT * 16 + ccol] = AC[0]; \
      zpart[kq][crow + 1][NT * 16 + ccol] = AC[1]; \
      zpart[kq][crow + 2][NT * 16 + ccol] = AC[2]; \
      zpart[kq][crow + 3][NT * 16 + ccol] = AC[3];
      DUMP(0, ac0) DUMP(1, ac1) DUMP(2, ac2) DUMP(3, ac3)
      DUMP(4, ac4) DUMP(5, ac5) DUMP(6, ac6) DUMP(7, ac7)
#undef DUMP
    }
    __syncthreads();   // barrier #1: also certifies all 32 flags seen collectively

    // cross-wave K reduction: local z-col = g*32 + (hg*2+j); bias already in xp
    float zc[4][2];
    #pragma unroll
    for (int g = 0; g < 4; ++g)
      #pragma unroll
      for (int j = 0; j < 2; ++j) {
        const int col = g * 32 + hg * 2 + j;
        zc[g][j] = (zpart[0][r][col] + zpart[1][r][col])
                 + (zpart[2][r][col] + zpart[3][r][col]);
      }

    float hv0, hv1;
    {
      const float zg = zc[0][0] + b2f((unsigned short)(xu0 & 0xffffu));
      const float zi = zc[1][0] + b2f((unsigned short)(xu1 & 0xffffu));
      const float zf = zc[2][0] + b2f((unsigned short)(xu2 & 0xffffu));
      const float zo = zc[3][0] + b2f((unsigned short)(xu3 & 0xffffu));
      cr0 = tanhf_(zg) * sigf(zi) + cr0 * sigf(zf);
      hv0 = tanhf_(cr0) * sigf(zo);
    }
    {
      const float zg = zc[0][1] + b2f((unsigned short)(xu0 >> 16));
      const float zi = zc[1][1] + b2f((unsigned short)(xu1 >> 16));
      const float zf = zc[2][1] + b2f((unsigned short)(xu2 >> 16));
      const float zo = zc[3][1] + b2f((unsigned short)(xu3 >> 16));
      cr1 = tanhf_(zg) * sigf(zi) + cr1 * sigf(zf);
      hv1 = tanhf_(cr1) * sigf(zo);
    }

    if (t < 510) {
      // h store (device scope) -> per-wave drain -> block sync -> flag broadcast
      const unsigned hp = (unsigned)f2b(hv0) | ((unsigned)f2b(hv1) << 16);
      unsigned short* hd = hbuf + ((t & 1) ^ 1) * 131072 + (size_t)grow * 1024 + hc0;
      asm volatile("global_store_dword %0, %1, off sc0 sc1" :: "v"(hd), "v"(hp) : "memory");
      asm volatile("s_waitcnt vmcnt(0)" ::: "memory");
      __syncthreads();   // barrier #2: all waves' h stores drained
      if (kq == 0 && lane < 32) {
        const unsigned g1 = (unsigned)(t + 1);
        asm volatile("global_store_dword %0, %1, off sc0 sc1" :: "v"(bcast), "v"(g1) : "memory");
      }
    }

    // out[t+1] = h after step t (out[0]=0 via memset); rides through poll phase
    float2 ho; ho.x = hv0; ho.y = hv1;
    *(float2*)(out + ((size_t)(t + 1) * 128 + grow) * 1024 + hc0) = ho;

    if (t < 510) {
      // prefetch next xproj (latency hides under the poll)
      const unsigned short* xpp = xproj + (size_t)(t + 1) * 524288 + xbase;
      asm volatile("global_load_dword %0, %1, off" : "=v"(xu0) : "v"(xpp));
      asm volatile("global_load_dword %0, %1, off" : "=v"(xu1) : "v"(xpp + 1024));
      asm volatile("global_load_dword %0, %1, off" : "=v"(xu2) : "v"(xpp + 2048));
      asm volatile("global_load_dword %0, %1, off" : "=v"(xu3) : "v"(xpp + 3072));
      // per-wave poll: wave kq waits only for ITS 8 producers (k-range deps)
      unsigned v;
      do {
        asm volatile("global_load_dword %0, %1, off sc0 sc1" : "=v"(v) : "v"(myf));
        asm volatile("s_waitcnt vmcnt(0)" ::: "memory");
      } while (__any((int)v <= t));
    }
  }
}

extern "C" void kernel_launch(void* const* d_in, const int* in_sizes, int n_in,
                              void* d_out, int out_size, void* d_ws, size_t ws_size,
                              hipStream_t stream) {
  (void)in_sizes; (void)n_in; (void)out_size; (void)ws_size;
  const float* embeds = (const float*)d_in[0];
  const float* Wx     = (const float*)d_in[1];
  const float* Wh     = (const float*)d_in[2];
  const float* bias   = (const float*)d_in[3];
  float* out = (float*)d_out;

  char* w = (char*)d_ws;
  unsigned short* eb  = (unsigned short*)(w);                 // 134,217,728 B
  unsigned short* WxT = (unsigned short*)(w + 134217728);     //   8,388,608 B
  unsigned short* Whp = (unsigned short*)(w + 142606336);     //   8,388,608 B
  unsigned short* xp  = (unsigned short*)(w + 150994944);     // 536,870,912 B
  unsigned short* hb  = (unsigned short*)(w + 687865856);     //     524,288 B
  unsigned*       fl  = (unsigned*)(w + 688390144);           //      32,768 B

  hipMemsetAsync(d_out, 0, (size_t)128 * 1024 * sizeof(float), stream);
  hipMemsetAsync(hb, 0, 524288, stream);
  hipMemsetAsync(fl, 0, 32768, stream);

  conv_e    <<<32768, 256, 0, stream>>>(embeds, eb);
  conv_wT   <<<1024,  256, 0, stream>>>(Wx, WxT);
  conv_whp  <<<2048,  256, 0, stream>>>(Wh, Whp);
  gemm_xproj<<<16384, 256, 0, stream>>>(eb, WxT, bias, xp);
  lstm_recur<<<256,   256, 0, stream>>>(xp, Whp, hb, out, fl);
}

// Round 12
// 2829.158 us; speedup vs baseline: 1.0837x; 1.0316x over previous
//
#include <hip/hip_runtime.h>
#include <hip/hip_bf16.h>

typedef __attribute__((ext_vector_type(8)))  short          bf16x8;
typedef __attribute__((ext_vector_type(4)))  float          f32x4;
typedef __attribute__((ext_vector_type(8)))  unsigned short us8;

__device__ __forceinline__ unsigned short f2b(float f) {
  union { __hip_bfloat16 h; unsigned short u; } v;
  v.h = __float2bfloat16(f);
  return v.u;
}
__device__ __forceinline__ float b2f(unsigned short u) {
  union { unsigned u; float f; } v; v.u = ((unsigned)u) << 16; return v.f;
}
__device__ __forceinline__ float sigf(float x) {
  return __builtin_amdgcn_rcpf(1.f + __expf(-x));
}
__device__ __forceinline__ float tanhf_(float x) {
  return 2.f * __builtin_amdgcn_rcpf(1.f + __expf(-2.f * x)) - 1.f;
}

// ---------- merged conversion kernel (same data as R9's separate convs) ----------
// blocks [0,32768): embeds -> A-frag-packed bf16
// blocks [32768,34816): W_x -> B-frag-packed bf16
// blocks [34816,36864): W_h -> packed B fragments (verified R6 layout)
__global__ __launch_bounds__(256) void conv_all(const float* __restrict__ embeds,
                                                const float* __restrict__ Wx,
                                                const float* __restrict__ Wh,
                                                unsigned short* __restrict__ ebf,
                                                unsigned short* __restrict__ wxf,
                                                unsigned short* __restrict__ whp) {
  const int b = blockIdx.x;
  if (b < 32768) {
    const int id = b * 256 + threadIdx.x;          // 8,388,608 units
    const int l  = id & 63;
    const int kt = (id >> 6) & 31;
    const int rt = id >> 11;
    const size_t src = ((size_t)(rt * 16 + (l & 15))) * 1024 + kt * 32 + (l >> 4) * 8;
    const float4 v0 = *(const float4*)(embeds + src);
    const float4 v1 = *(const float4*)(embeds + src + 4);
    us8 o;
    o[0]=f2b(v0.x); o[1]=f2b(v0.y); o[2]=f2b(v0.z); o[3]=f2b(v0.w);
    o[4]=f2b(v1.x); o[5]=f2b(v1.y); o[6]=f2b(v1.z); o[7]=f2b(v1.w);
    *(us8*)(ebf + (size_t)id * 8) = o;
  } else if (b < 34816) {
    const int id = (b - 32768) * 256 + threadIdx.x; // 524288 units
    const int l  = id & 63;
    const int kt = (id >> 6) & 31;
    const int c  = id >> 11;
    const int col = c * 16 + (l & 15);
    const int k0 = kt * 32 + (l >> 4) * 8;
    us8 o;
    #pragma unroll
    for (int j = 0; j < 8; ++j) o[j] = f2b(Wx[(size_t)(k0 + j) * 4096 + col]);
    *(us8*)(wxf + (size_t)id * 8) = o;
  } else {
    const int id = (b - 34816) * 256 + threadIdx.x; // 524288 units
    const int l  = id & 63;
    const int kt = (id >> 6) & 7;
    const int nt = (id >> 9) & 7;
    const int kq = (id >> 12) & 3;
    const int n  = id >> 14;
    const int zi = nt * 16 + (l & 15);
    const int col = (zi >> 5) * 1024 + n * 32 + (zi & 31);
    const int k0 = kq * 256 + kt * 32 + (l >> 4) * 8;
    us8 o;
    #pragma unroll
    for (int j = 0; j < 8; ++j) o[j] = f2b(Wh[(size_t)(k0 + j) * 4096 + col]);
    *(us8*)(whp + (size_t)id * 8) = o;
  }
}

// ---------- register-only fragment-packed xproj GEMM (ablation of worker path) ----
// 8192 blocks x 4 waves; wave w = blockIdx*4+wv handles tile id=w: 64 rows x 128
// cols, K=1024. Identical data path to R8/R9/R11's worker waves, run standalone.
__global__ __launch_bounds__(256, 2) void gemm_xproj_reg(
    const unsigned short* __restrict__ ebf,
    const unsigned short* __restrict__ wxf,
    const float* __restrict__ bias,
    unsigned short* __restrict__ xp) {
  const int lane = threadIdx.x & 63;
  const int wv = threadIdx.x >> 6;
  const int w = blockIdx.x * 4 + wv;           // tile id 0..32767
  const int ct = w & 31;                       // 128-col tile
  const int rt = w >> 5;                       // 64-row tile

  float bvf[8];
  #pragma unroll
  for (int nt = 0; nt < 8; ++nt) bvf[nt] = bias[ct * 128 + nt * 16 + (lane & 15)];

  f32x4 acc[4][8];
  #pragma unroll
  for (int a = 0; a < 4; ++a)
    #pragma unroll
    for (int nt = 0; nt < 8; ++nt) acc[a][nt] = f32x4{0.f,0.f,0.f,0.f};

  for (int kt = 0; kt < 32; ++kt) {
    bf16x8 af[4], bfr[8];
    #pragma unroll
    for (int a = 0; a < 4; ++a)
      af[a] = *(const bf16x8*)(ebf + (size_t)((4 * rt + a) * 32 + kt) * 512 + lane * 8);
    #pragma unroll
    for (int nt = 0; nt < 8; ++nt)
      bfr[nt] = *(const bf16x8*)(wxf + (size_t)((ct * 8 + nt) * 32 + kt) * 512 + lane * 8);
    #pragma unroll
    for (int a = 0; a < 4; ++a)
      #pragma unroll
      for (int nt = 0; nt < 8; ++nt)
        acc[a][nt] = __builtin_amdgcn_mfma_f32_16x16x32_bf16(af[a], bfr[nt], acc[a][nt], 0, 0, 0);
  }

  // epilogue: C/D col=lane&15, row=(lane>>4)*4+rr; bias folded HERE (only here)
  #pragma unroll
  for (int a = 0; a < 4; ++a) {
    const int row0 = rt * 64 + a * 16 + (lane >> 4) * 4;
    #pragma unroll
    for (int nt = 0; nt < 8; ++nt) {
      const int col = ct * 128 + nt * 16 + (lane & 15);
      #pragma unroll
      for (int rr = 0; rr < 4; ++rr)
        xp[(size_t)(row0 + rr) * 4096 + col] = f2b(acc[a][nt][rr] + bvf[nt]);
    }
  }
}

// ---------- persistent recurrence kernel (R10, byte-identical — PASSED) ----------
__global__ __launch_bounds__(256, 1) void lstm_recur(
    const unsigned short* __restrict__ xproj,  // [512*128][4096] bf16, bias folded
    const unsigned short* __restrict__ Wp,     // packed fragments
    unsigned short* __restrict__ hbuf,         // [2][128][1024] bf16 row-major
    float* __restrict__ out,                   // [512][128][1024]
    unsigned* __restrict__ flags) {            // [256][32] private mailboxes
  __shared__ float zpart[10][16][132];         // [0..3] used; oversized -> 1 block/CU
  const int tid = threadIdx.x;
  const int lane = tid & 63;
  const int kq = tid >> 6;                     // wave = K-quarter
  const int m = blockIdx.x >> 5;               // group / 16-row batch stripe
  const int n = blockIdx.x & 31;               // 128-z-col slot

  // W_h fragments -> VGPRs (64 x bf16x8, held whole kernel)
  bf16x8 wf[64];
  {
    const unsigned short* wb = Wp + ((size_t)(n * 4 + kq) * 64) * 512 + lane * 8;
    #pragma unroll
    for (int f = 0; f < 64; ++f) wf[f] = *(const bf16x8*)(wb + f * 512);
  }

  const int r    = tid >> 4;                   // row within stripe (0..15)
  const int hg   = tid & 15;                   // h-col pair group
  const int hc0  = n * 32 + hg * 2;            // h col (0..1023)
  const int grow = m * 16 + r;                 // global batch row

  float cr0 = 0.f, cr1 = 0.f;
  const size_t xbase = (size_t)grow * 4096 + hc0;
  unsigned* bcast = flags + (m * 32 + (lane & 31)) * 32 + n;  // producer->consumer slots
  // per-wave dependency poll: wave kq watches producers kq*8 .. kq*8+7
  const unsigned* myf = flags + (size_t)(m * 32 + n) * 32 + kq * 8 + (lane & 7);

  // prologue: xproj loads for step 0
  unsigned xu0, xu1, xu2, xu3;
  {
    const unsigned short* xpp = xproj + xbase;
    asm volatile("global_load_dword %0, %1, off" : "=v"(xu0) : "v"(xpp));
    asm volatile("global_load_dword %0, %1, off" : "=v"(xu1) : "v"(xpp + 1024));
    asm volatile("global_load_dword %0, %1, off" : "=v"(xu2) : "v"(xpp + 2048));
    asm volatile("global_load_dword %0, %1, off" : "=v"(xu3) : "v"(xpp + 3072));
  }

  // A-frag addr: row (lane&15) of stripe, k = kq*256 + (lane>>4)*8 (+kt*32 imm)
  const size_t aoff = ((size_t)(m * 16 + (lane & 15))) * 1024 + kq * 256 + (lane >> 4) * 8;

  for (int t = 0; t < 511; ++t) {
    const unsigned short* ab = hbuf + (t & 1) * 131072 + aoff;

    bf16x8 av0, av1, av2, av3, av4, av5, av6, av7;
    __builtin_amdgcn_sched_barrier(0);
    asm volatile("global_load_dwordx4 %0, %1, off sc0 sc1"            : "=v"(av0) : "v"(ab));
    asm volatile("global_load_dwordx4 %0, %1, off offset:64 sc0 sc1"  : "=v"(av1) : "v"(ab));
    asm volatile("global_load_dwordx4 %0, %1, off offset:128 sc0 sc1" : "=v"(av2) : "v"(ab));
    asm volatile("global_load_dwordx4 %0, %1, off offset:192 sc0 sc1" : "=v"(av3) : "v"(ab));
    asm volatile("global_load_dwordx4 %0, %1, off offset:256 sc0 sc1" : "=v"(av4) : "v"(ab));
    asm volatile("global_load_dwordx4 %0, %1, off offset:320 sc0 sc1" : "=v"(av5) : "v"(ab));
    asm volatile("global_load_dwordx4 %0, %1, off offset:384 sc0 sc1" : "=v"(av6) : "v"(ab));
    asm volatile("global_load_dwordx4 %0, %1, off offset:448 sc0 sc1" : "=v"(av7) : "v"(ab));
    asm volatile("s_waitcnt vmcnt(0)" ::: "memory");
    __builtin_amdgcn_sched_barrier(0);

    // MFMA: 8 n-tiles x 8 k-tiles of 16x16x32; acc reuse distance 8
    f32x4 ac0 = {0.f,0.f,0.f,0.f}, ac1 = {0.f,0.f,0.f,0.f};
    f32x4 ac2 = {0.f,0.f,0.f,0.f}, ac3 = {0.f,0.f,0.f,0.f};
    f32x4 ac4 = {0.f,0.f,0.f,0.f}, ac5 = {0.f,0.f,0.f,0.f};
    f32x4 ac6 = {0.f,0.f,0.f,0.f}, ac7 = {0.f,0.f,0.f,0.f};
#define MF_STEP(AV, KT) \
    ac0 = __builtin_amdgcn_mfma_f32_16x16x32_bf16(AV, wf[ 0 + KT], ac0, 0, 0, 0); \
    ac1 = __builtin_amdgcn_mfma_f32_16x16x32_bf16(AV, wf[ 8 + KT], ac1, 0, 0, 0); \
    ac2 = __builtin_amdgcn_mfma_f32_16x16x32_bf16(AV, wf[16 + KT], ac2, 0, 0, 0); \
    ac3 = __builtin_amdgcn_mfma_f32_16x16x32_bf16(AV, wf[24 + KT], ac3, 0, 0, 0); \
    ac4 = __builtin_amdgcn_mfma_f32_16x16x32_bf16(AV, wf[32 + KT], ac4, 0, 0, 0); \
    ac5 = __builtin_amdgcn_mfma_f32_16x16x32_bf16(AV, wf[40 + KT], ac5, 0, 0, 0); \
    ac6 = __builtin_amdgcn_mfma_f32_16x16x32_bf16(AV, wf[48 + KT], ac6, 0, 0, 0); \
    ac7 = __builtin_amdgcn_mfma_f32_16x16x32_bf16(AV, wf[56 + KT], ac7, 0, 0, 0);
    MF_STEP(av0, 0) MF_STEP(av1, 1) MF_STEP(av2, 2) MF_STEP(av3, 3)
    MF_STEP(av4, 4) MF_STEP(av5, 5) MF_STEP(av6, 6) MF_STEP(av7, 7)
#undef MF_STEP

    // dump partials: 16x16 C/D: col=lane&15, row=(lane>>4)*4+reg
    {
      const int crow = (lane >> 4) * 4, ccol = lane & 15;
#define DUMP(NT, AC) \
      zpart[kq][crow + 0][NT * 16 + ccol] = AC[0]; \
      zpart[kq][crow + 1][NT * 16 + ccol] = AC[1]; \
      zpart[kq][crow + 2][NT * 16 + ccol] = AC[2]; \
      zpart[kq][crow + 3][NT * 16 + ccol] = AC[3];
      DUMP(0, ac0) DUMP(1, ac1) DUMP(2, ac2) DUMP(3, ac3)
      DUMP(4, ac4) DUMP(5, ac5) DUMP(6, ac6) DUMP(7, ac7)
#undef DUMP
    }
    __syncthreads();   // barrier #1

    // cross-wave K reduction: local z-col = g*32 + (hg*2+j); bias already in xp
    float zc[4][2];
    #pragma unroll
    for (int g = 0; g < 4; ++g)
      #pragma unroll
      for (int j = 0; j < 2; ++j) {
        const int col = g * 32 + hg * 2 + j;
        zc[g][j] = (zpart[0][r][col] + zpart[1][r][col])
                 + (zpart[2][r][col] + zpart[3][r][col]);
      }

    float hv0, hv1;
    {
      const float zg = zc[0][0] + b2f((unsigned short)(xu0 & 0xffffu));
      const float zi = zc[1][0] + b2f((unsigned short)(xu1 & 0xffffu));
      const float zf = zc[2][0] + b2f((unsigned short)(xu2 & 0xffffu));
      const float zo = zc[3][0] + b2f((unsigned short)(xu3 & 0xffffu));
      cr0 = tanhf_(zg) * sigf(zi) + cr0 * sigf(zf);
      hv0 = tanhf_(cr0) * sigf(zo);
    }
    {
      const float zg = zc[0][1] + b2f((unsigned short)(xu0 >> 16));
      const float zi = zc[1][1] + b2f((unsigned short)(xu1 >> 16));
      const float zf = zc[2][1] + b2f((unsigned short)(xu2 >> 16));
      const float zo = zc[3][1] + b2f((unsigned short)(xu3 >> 16));
      cr1 = tanhf_(zg) * sigf(zi) + cr1 * sigf(zf);
      hv1 = tanhf_(cr1) * sigf(zo);
    }

    if (t < 510) {
      // h store (device scope) -> per-wave drain -> block sync -> flag broadcast
      const unsigned hp = (unsigned)f2b(hv0) | ((unsigned)f2b(hv1) << 16);
      unsigned short* hd = hbuf + ((t & 1) ^ 1) * 131072 + (size_t)grow * 1024 + hc0;
      asm volatile("global_store_dword %0, %1, off sc0 sc1" :: "v"(hd), "v"(hp) : "memory");
      asm volatile("s_waitcnt vmcnt(0)" ::: "memory");
      __syncthreads();   // barrier #2
      if (kq == 0 && lane < 32) {
        const unsigned g1 = (unsigned)(t + 1);
        asm volatile("global_store_dword %0, %1, off sc0 sc1" :: "v"(bcast), "v"(g1) : "memory");
      }
    }

    // out[t+1] = h after step t (out[0]=0 via memset); rides through poll phase
    float2 ho; ho.x = hv0; ho.y = hv1;
    *(float2*)(out + ((size_t)(t + 1) * 128 + grow) * 1024 + hc0) = ho;

    if (t < 510) {
      // prefetch next xproj (latency hides under the poll)
      const unsigned short* xpp = xproj + (size_t)(t + 1) * 524288 + xbase;
      asm volatile("global_load_dword %0, %1, off" : "=v"(xu0) : "v"(xpp));
      asm volatile("global_load_dword %0, %1, off" : "=v"(xu1) : "v"(xpp + 1024));
      asm volatile("global_load_dword %0, %1, off" : "=v"(xu2) : "v"(xpp + 2048));
      asm volatile("global_load_dword %0, %1, off" : "=v"(xu3) : "v"(xpp + 3072));
      // per-wave poll: wave kq waits only for ITS 8 producers (k-range deps)
      unsigned v;
      do {
        asm volatile("global_load_dword %0, %1, off sc0 sc1" : "=v"(v) : "v"(myf));
        asm volatile("s_waitcnt vmcnt(0)" ::: "memory");
      } while (__any((int)v <= t));
    }
  }
}

extern "C" void kernel_launch(void* const* d_in, const int* in_sizes, int n_in,
                              void* d_out, int out_size, void* d_ws, size_t ws_size,
                              hipStream_t stream) {
  (void)in_sizes; (void)n_in; (void)out_size; (void)ws_size;
  const float* embeds = (const float*)d_in[0];
  const float* Wx     = (const float*)d_in[1];
  const float* Wh     = (const float*)d_in[2];
  const float* bias   = (const float*)d_in[3];
  float* out = (float*)d_out;

  char* w = (char*)d_ws;
  unsigned short* ebf = (unsigned short*)(w);                 // 134,217,728 B
  unsigned short* wxf = (unsigned short*)(w + 134217728);     //   8,388,608 B
  unsigned short* whp = (unsigned short*)(w + 142606336);     //   8,388,608 B
  unsigned short* xpb = (unsigned short*)(w + 150994944);     // 536,870,912 B
  unsigned short* hb  = (unsigned short*)(w + 687865856);     //     524,288 B
  unsigned*       fl  = (unsigned*)(w + 688390144);           //      32,768 B

  hipMemsetAsync(d_out, 0, (size_t)128 * 1024 * sizeof(float), stream);
  hipMemsetAsync(hb, 0, 524288, stream);
  hipMemsetAsync(fl, 0, 32768, stream);

  conv_all      <<<36864, 256, 0, stream>>>(embeds, Wx, Wh, ebf, wxf, whp);
  gemm_xproj_reg<<<8192,  256, 0, stream>>>(ebf, wxf, bias, xpb);
  lstm_recur    <<<256,   256, 0, stream>>>(xpb, whp, hb, out, fl);
}